// Round 1
// baseline (152.266 us; speedup 1.0000x reference)
//
#include <hip/hip_runtime.h>

#define BB   4
#define QS   512
#define KSZ  1024
#define DD   512
#define HH   128
#define DVV  512

typedef unsigned int uint;
typedef unsigned short ushort;
typedef unsigned long long ull;
typedef __attribute__((ext_vector_type(8)))  short short8;   // 8 bf16 (4 VGPRs)
typedef __attribute__((ext_vector_type(16))) float f32x16;   // MFMA 32x32 acc

__device__ __forceinline__ float rcp_fast(float x)  { return __builtin_amdgcn_rcpf(x); }
__device__ __forceinline__ float exp2_fast(float x) { return __builtin_amdgcn_exp2f(x); }

// split fp32 -> bf16 hi (truncate) + bf16 lo (residual); ~2^-17 rel combined
__device__ __forceinline__ void split1(float v, ushort& h, ushort& l) {
    uint u = __float_as_uint(v);
    h = (ushort)(u >> 16);
    float r = v - __uint_as_float(u & 0xffff0000u);
    l = (ushort)(__float_as_uint(r) >> 16);
}

// split_kernel grid segments (q/k/W only; V^T lives in projvt_kernel)
#define NSQ  (BB * QS * DD / 4 / 256)     // 1024
#define NSK  (BB * KSZ * DD / 4 / 256)    // 2048
#define NWT  128                          // 64 per W
#define NPJ  192                          // proj blocks (768 waves)
#define NVT  (BB * (KSZ / 32) * (DVV / 32))  // 2048 V-transpose blocks

// ---------------------------------------------------------------------------
// Kernel 1: bf16 pre-split of q, k (element-wise) and W_q/W_k (transpose to
// [h][d]). Pure memory-bound, ~25 MB.
// ---------------------------------------------------------------------------
__global__ __launch_bounds__(256) void split_kernel(
    const float* __restrict__ q, const float* __restrict__ k,
    const float* __restrict__ Wq, const float* __restrict__ Wk,
    ushort* __restrict__ qh, ushort* __restrict__ ql,
    ushort* __restrict__ kh, ushort* __restrict__ kl,
    ushort* __restrict__ wqh, ushort* __restrict__ wql,
    ushort* __restrict__ wkh, ushort* __restrict__ wkl)
{
    const int id  = blockIdx.x;
    const int tid = threadIdx.x;

    if (id < NSQ + NSK) {
        const float* src; ushort* dh; ushort* dl; size_t i;
        if (id < NSQ) { src = q; dh = qh; dl = ql; i = (size_t)id * 256 + tid; }
        else          { src = k; dh = kh; dl = kl; i = (size_t)(id - NSQ) * 256 + tid; }
        float4 v = ((const float4*)src)[i];
        ushort h0,h1,h2,h3,l0,l1,l2,l3;
        split1(v.x,h0,l0); split1(v.y,h1,l1); split1(v.z,h2,l2); split1(v.w,h3,l3);
        *(ushort4*)&dh[i * 4] = make_ushort4(h0,h1,h2,h3);
        *(ushort4*)&dl[i * 4] = make_ushort4(l0,l1,l2,l3);
        return;
    }
    // ---- W transpose + split: [512][128] -> [128][512] hi/lo ----
    __shared__ float Ts[32][33];
    int t = id - (NSQ + NSK);
    const float* W; ushort* dh; ushort* dl;
    if (t < 64) { W = Wq; dh = wqh; dl = wql; }
    else        { W = Wk; dh = wkh; dl = wkl; t -= 64; }
    const int d0 = (t >> 2) * 32, h0 = (t & 3) * 32;
    {
        const int dd = tid >> 3, c4 = (tid & 7) * 4;
        float4 v = *(const float4*)&W[(size_t)(d0 + dd) * HH + h0 + c4];
        Ts[dd][c4 + 0] = v.x; Ts[dd][c4 + 1] = v.y;
        Ts[dd][c4 + 2] = v.z; Ts[dd][c4 + 3] = v.w;
    }
    __syncthreads();
    {
        const int hh = tid >> 3, d4 = (tid & 7) * 4;
        ushort h[4], l[4];
        #pragma unroll
        for (int i = 0; i < 4; i++) split1(Ts[d4 + i][hh], h[i], l[i]);
        size_t o = (size_t)(h0 + hh) * DD + d0 + d4;
        *(ushort4*)&dh[o] = make_ushort4(h[0], h[1], h[2], h[3]);
        *(ushort4*)&dl[o] = make_ushort4(l[0], l[1], l[2], l[3]);
    }
}

// ---------------------------------------------------------------------------
// Kernel 2 (fused): blocks [0,NPJ) = projection via MFMA (pre-split bf16
// operands, b128 loads, 3 MFMAs/k16) + exp(2x). Blocks [NPJ,+NVT) = V
// transpose+split (memory-bound backfill behind proj's 192-block tail).
// ---------------------------------------------------------------------------
__global__ __launch_bounds__(256) void projvt_kernel(
    const ushort* __restrict__ qh, const ushort* __restrict__ ql,
    const ushort* __restrict__ kh, const ushort* __restrict__ kl,
    const ushort* __restrict__ wqh, const ushort* __restrict__ wql,
    const ushort* __restrict__ wkh, const ushort* __restrict__ wkl,
    const float* __restrict__ val,
    float* __restrict__ eq, float* __restrict__ ek,
    ushort* __restrict__ vhi, ushort* __restrict__ vlo)
{
    const int id  = blockIdx.x;
    const int tid = threadIdx.x;

    if (id >= NPJ) {
        __shared__ float Ts[32][33];
        const int t   = id - NPJ;
        const int b   = t >> 9;
        const int rem = t & 511;
        const int k0  = (rem >> 4) * 32;
        const int n0  = (rem & 15) * 32;
        {
            const int kk = tid >> 3, n4 = (tid & 7) * 4;
            float4 v = *(const float4*)&val[((size_t)b * KSZ + k0 + kk) * DVV + n0 + n4];
            Ts[kk][n4 + 0] = v.x; Ts[kk][n4 + 1] = v.y;
            Ts[kk][n4 + 2] = v.z; Ts[kk][n4 + 3] = v.w;
        }
        __syncthreads();
        {
            const int nn = tid >> 3, k4 = (tid & 7) * 4;
            ushort h[4], l[4];
            #pragma unroll
            for (int i = 0; i < 4; i++) split1(Ts[k4 + i][nn], h[i], l[i]);
            size_t o = ((size_t)b * DVV + n0 + nn) * KSZ + k0 + k4;
            *(ushort4*)&vhi[o] = make_ushort4(h[0], h[1], h[2], h[3]);
            *(ushort4*)&vlo[o] = make_ushort4(l[0], l[1], l[2], l[3]);
        }
        return;
    }

    // ---- projection: eq/ek[m][h] = exp2(C2L * sum_d A[m][d]*W[d][h]) ----
    const int w = tid >> 6, lane = tid & 63;
    const int row = lane & 31, kg = lane >> 5;
    const int gw = id * 4 + w;                  // 0..767

    const ushort *pa_h, *pa_l, *pb_h, *pb_l; float* op; int m0, nt;
    if (gw < 256) {
        m0 = (gw >> 2) * 32; nt = gw & 3;
        pa_h = qh; pa_l = ql; pb_h = wqh; pb_l = wql; op = eq;
    } else {
        const int g = gw - 256;
        m0 = (g >> 2) * 32; nt = g & 3;
        pa_h = kh; pa_l = kl; pb_h = wkh; pb_l = wkl; op = ek;
    }

    const ushort* ah_p = pa_h + (size_t)(m0 + row) * DD + kg * 8;
    const ushort* al_p = pa_l + (size_t)(m0 + row) * DD + kg * 8;
    const ushort* bh_p = pb_h + (size_t)(nt * 32 + row) * DD + kg * 8;
    const ushort* bl_p = pb_l + (size_t)(nt * 32 + row) * DD + kg * 8;

    f32x16 acc;
    #pragma unroll
    for (int i = 0; i < 16; i++) acc[i] = 0.f;

    #pragma unroll 8
    for (int ks = 0; ks < DD; ks += 16) {
        short8 ah = *(const short8*)(ah_p + ks);
        short8 al = *(const short8*)(al_p + ks);
        short8 bh = *(const short8*)(bh_p + ks);
        short8 bl = *(const short8*)(bl_p + ks);
        acc = __builtin_amdgcn_mfma_f32_32x32x16_bf16(ah, bh, acc, 0, 0, 0);
        acc = __builtin_amdgcn_mfma_f32_32x32x16_bf16(ah, bl, acc, 0, 0, 0);
        acc = __builtin_amdgcn_mfma_f32_32x32x16_bf16(al, bh, acc, 0, 0, 0);
    }

    const float C2L = 2.8853900817779268f;  // 2*log2(e)
    float* ob = op + (size_t)m0 * HH + nt * 32;
    #pragma unroll
    for (int r = 0; r < 16; r++) {
        const int rb = (r & 3) + 8 * (r >> 2) + 4 * kg;
        ob[(size_t)rb * HH + row] = exp2_fast(acc[r] * C2L);
    }
}

// ---------------------------------------------------------------------------
// Kernel 3 (NEW, fused scores+PV): one block per (b, q-tile 64, k-part 128).
// Grid 256 = 1 block/CU, 512 threads (8 waves, 2/SIMD).
// Per 32-k subtile: scores phase (VALU, ~2.4K instr/thread over 4 subtiles)
// computes P hi/lo into LDS; MFMA phase does P@V^T with B-fragments
// PREFETCHED from global into registers at the top of the scores phase
// (latency hidden under ~10K VALU cycles; each 64B V^T line fully consumed).
// ek subtile s+1 reg-staged during scores s (T14). K-split partials written
// to opart (f32, deterministic); rowsums to rsp[bq][8].
// blockIdx encoding: bk = id&31 -> id%8 = bk%8, so all 8 q-tile blocks
// sharing a (b,kp) V^T/ek slice land on the same XCD (L2-local, ~1 MB/XCD).
// ---------------------------------------------------------------------------
__global__ __launch_bounds__(512, 2) void spv_kernel(
    const float* __restrict__ eq, const float* __restrict__ ek,
    const float* __restrict__ wv,
    const ushort* __restrict__ vhi, const ushort* __restrict__ vlo,
    float* __restrict__ opart, float* __restrict__ rsp)
{
    __shared__ float  eqs[64][132];   // 33792 B, odd-ish stride (132%32=4 -> 2-way max)
    __shared__ float  eks[32][132];   // 16896 B
    __shared__ ushort PhS[64][36];    // 4608 B, stride 18 words (2-way = free)
    __shared__ ushort PlS[64][36];    // 4608 B   (total 59904 B < 64 KB)

    const int id  = blockIdx.x;
    const int bk  = id & 31;          // same bk -> same XCD
    const int qt  = id >> 5;
    const int b   = bk >> 3;
    const int kp  = bk & 7;

    const int tid  = threadIdx.x;
    const int w    = tid >> 6, lane = tid & 63;
    const int col  = lane & 31, kg = lane >> 5;
    const int wq   = (w & 1) * 32;          // q half for MFMA
    const int wn   = (w >> 1) * 128;        // n quarter for MFMA
    const int tq   = tid >> 4;              // scores: q rows tq, tq+32
    const int tk   = tid & 15;              // scores: k cols tk, tk+16

    // ---- prologue: stage eq tile [64][128] + ek subtile 0 [32][128] ----
    const float* eqg = eq + ((size_t)b * QS + qt * 64) * HH;
    #pragma unroll
    for (int i = 0; i < 4; i++) {
        int f = tid + i * 512;
        int row = f >> 5, c4 = (f & 31) * 4;
        *(float4*)&eqs[row][c4] = *(const float4*)&eqg[(size_t)row * HH + c4];
    }
    const float* ekg = ek + ((size_t)b * KSZ + kp * 128) * HH;
    #pragma unroll
    for (int i = 0; i < 2; i++) {
        int f = tid + i * 512;
        int row = f >> 5, c4 = (f & 31) * 4;
        *(float4*)&eks[row][c4] = *(const float4*)&ekg[(size_t)row * HH + c4];
    }
    __syncthreads();

    f32x16 acc[4];
    #pragma unroll
    for (int n = 0; n < 4; n++) {
        #pragma unroll
        for (int i = 0; i < 16; i++) acc[n][i] = 0.f;
    }
    float rowacc0 = 0.f, rowacc1 = 0.f;

    // per-lane V^T base: row = b*DVV + wn + col, k base = kp*128
    const size_t vrow0 = ((size_t)b * DVV + wn + col) * KSZ + kp * 128;
    const ushort* vh_p = vhi + vrow0;
    const ushort* vl_p = vlo + vrow0;

#define SGROUP(eqv, ekv, sacc) { \
    float u0 = fminf(fmaf((eqv).x, (ekv).x, 1.0f), 3e7f); \
    float u1 = fminf(fmaf((eqv).y, (ekv).y, 1.0f), 3e7f); \
    float u2 = fminf(fmaf((eqv).z, (ekv).z, 1.0f), 3e7f); \
    float u3 = fminf(fmaf((eqv).w, (ekv).w, 1.0f), 3e7f); \
    float p01 = u0 * u1, p23 = u2 * u3; \
    float n01 = fmaf(wv4.x, u1, wv4.y * u0); \
    float n23 = fmaf(wv4.z, u3, wv4.w * u2); \
    float Nn = fmaf(n01, p23, n23 * p01); \
    sacc = fmaf(Nn, rcp_fast(p01 * p23), sacc); }

    for (int s = 0; s < 4; s++) {
        // -- issue B-fragment global loads for THIS subtile (used after bar1) --
        uint4 bhf[8], blf[8];
        #pragma unroll
        for (int nb = 0; nb < 4; nb++) {
            #pragma unroll
            for (int k2 = 0; k2 < 2; k2++) {
                const size_t o = (size_t)(nb * 32) * KSZ + s * 32 + k2 * 16 + kg * 8;
                bhf[nb * 2 + k2] = *(const uint4*)(vh_p + o);
                blf[nb * 2 + k2] = *(const uint4*)(vl_p + o);
            }
        }
        // -- issue ek loads for NEXT subtile (written to LDS after bar1) --
        float4 eknxt0, eknxt1;
        if (s < 3) {
            int f0 = tid, f1 = tid + 512;
            eknxt0 = *(const float4*)&ekg[(size_t)((s + 1) * 32 + (f0 >> 5)) * HH + (f0 & 31) * 4];
            eknxt1 = *(const float4*)&ekg[(size_t)((s + 1) * 32 + (f1 >> 5)) * HH + (f1 & 31) * 4];
        }

        // ---- scores: 64q x 32k, 4 (q,k) pairs per thread ----
        float s00 = 0.f, s01 = 0.f, s10 = 0.f, s11 = 0.f;
        #pragma unroll 2
        for (int h = 0; h < HH; h += 4) {
            float4 wv4 = *(const float4*)&wv[h];      // uniform -> s_load
            float4 eqa = *(const float4*)&eqs[tq][h];
            float4 eqb = *(const float4*)&eqs[tq + 32][h];
            float4 eka = *(const float4*)&eks[tk][h];
            float4 ekb = *(const float4*)&eks[tk + 16][h];
            SGROUP(eqa, eka, s00);
            SGROUP(eqa, ekb, s01);
            SGROUP(eqb, eka, s10);
            SGROUP(eqb, ekb, s11);
        }
        {
            const float CN = -2.8853900817779268f;  // -2*log2(e)
            float p00 = exp2_fast(s00 * CN);
            float p01v = exp2_fast(s01 * CN);
            float p10 = exp2_fast(s10 * CN);
            float p11 = exp2_fast(s11 * CN);
            ushort hh, ll;
            split1(p00,  hh, ll); PhS[tq][tk]           = hh; PlS[tq][tk]           = ll;
            split1(p01v, hh, ll); PhS[tq][tk + 16]      = hh; PlS[tq][tk + 16]      = ll;
            split1(p10,  hh, ll); PhS[tq + 32][tk]      = hh; PlS[tq + 32][tk]      = ll;
            split1(p11,  hh, ll); PhS[tq + 32][tk + 16] = hh; PlS[tq + 32][tk + 16] = ll;
            rowacc0 += p00 + p01v;
            rowacc1 += p10 + p11;
        }
        __syncthreads();   // P ready; eks free to overwrite

        // -- stage ek s+1 into LDS (regs loaded ~10K cycles ago) --
        if (s < 3) {
            int f0 = tid, f1 = tid + 512;
            *(float4*)&eks[f0 >> 5][(f0 & 31) * 4] = eknxt0;
            *(float4*)&eks[f1 >> 5][(f1 & 31) * 4] = eknxt1;
        }

        // ---- MFMA: P(64x32) @ V^T fragments (regs) ----
        #pragma unroll
        for (int k2 = 0; k2 < 2; k2++) {
            short8 ah, al;
            { const ull* p = (const ull*)&PhS[wq + col][k2 * 16 + kg * 8];
              ((ull*)&ah)[0] = p[0]; ((ull*)&ah)[1] = p[1]; }
            { const ull* p = (const ull*)&PlS[wq + col][k2 * 16 + kg * 8];
              ((ull*)&al)[0] = p[0]; ((ull*)&al)[1] = p[1]; }
            #pragma unroll
            for (int nb = 0; nb < 4; nb++) {
                short8 vh = *(const short8*)&bhf[nb * 2 + k2];
                short8 vl = *(const short8*)&blf[nb * 2 + k2];
                acc[nb] = __builtin_amdgcn_mfma_f32_32x32x16_bf16(ah, vh, acc[nb], 0, 0, 0);
                acc[nb] = __builtin_amdgcn_mfma_f32_32x32x16_bf16(ah, vl, acc[nb], 0, 0, 0);
                acc[nb] = __builtin_amdgcn_mfma_f32_32x32x16_bf16(al, vh, acc[nb], 0, 0, 0);
            }
        }
        __syncthreads();   // all waves done with PhS/eks before next scores
    }
#undef SGROUP

    // ---- rowsum partials: reduce across the 16 k-threads of each q row ----
    #pragma unroll
    for (int m = 8; m; m >>= 1) {
        rowacc0 += __shfl_xor(rowacc0, m);
        rowacc1 += __shfl_xor(rowacc1, m);
    }
    if (tk == 0) {
        rsp[((size_t)b * QS + qt * 64 + tq) * 8 + kp]      = rowacc0;
        rsp[((size_t)b * QS + qt * 64 + tq + 32) * 8 + kp] = rowacc1;
    }

    // ---- partial-output store: opart[kp][b][q][n] ----
    float* ob = opart + (((size_t)kp * BB + b) * QS + qt * 64 + wq) * DVV + wn;
    #pragma unroll
    for (int nb = 0; nb < 4; nb++) {
        #pragma unroll
        for (int r = 0; r < 16; r++) {
            const int rb = (r & 3) + 8 * (r >> 2) + 4 * kg;
            ob[(size_t)rb * DVV + nb * 32 + col] = acc[nb][r];
        }
    }
}

// ---------------------------------------------------------------------------
// Kernel 4: out[b][q][n] = sum_kp opart / sum_kp rsp. ~36 MB, HBM/L3-bound.
// ---------------------------------------------------------------------------
__global__ __launch_bounds__(256) void norm_kernel(
    const float* __restrict__ opart, const float* __restrict__ rsp,
    float* __restrict__ outp)
{
    const int i  = blockIdx.x * 256 + threadIdx.x;   // 262144 f4 totals
    const int n4 = (i & 127) * 4;
    const int q  = (i >> 7) & (QS - 1);
    const int b  = i >> 16;

    const float* rp = rsp + ((size_t)b * QS + q) * 8;
    float4 r0 = *(const float4*)rp;
    float4 r1 = *(const float4*)(rp + 4);
    float inv = rcp_fast(r0.x + r0.y + r0.z + r0.w + r1.x + r1.y + r1.z + r1.w);

    float ox = 0.f, oy = 0.f, oz = 0.f, ow = 0.f;
    #pragma unroll
    for (int kp = 0; kp < 8; kp++) {
        float4 v = *(const float4*)&opart[(((size_t)kp * BB + b) * QS + q) * DVV + n4];
        ox += v.x; oy += v.y; oz += v.z; ow += v.w;
    }
    float4 res = make_float4(ox * inv, oy * inv, oz * inv, ow * inv);
    *(float4*)&outp[((size_t)b * QS + q) * DVV + n4] = res;
}

// ---------------------------------------------------------------------------
extern "C" void kernel_launch(void* const* d_in, const int* in_sizes, int n_in,
                              void* d_out, int out_size, void* d_ws, size_t ws_size,
                              hipStream_t stream)
{
    const float* queries = (const float*)d_in[0];
    const float* keys    = (const float*)d_in[1];
    const float* values  = (const float*)d_in[2];
    const float* Wq      = (const float*)d_in[3];
    const float* Wk      = (const float*)d_in[4];
    const float* wv      = (const float*)d_in[5];
    float* out = (float*)d_out;

    // float region
    float*  eq    = (float*)d_ws;
    float*  ek    = eq  + (size_t)BB * QS * HH;
    float*  rsp   = ek  + (size_t)BB * KSZ * HH;            // [b*Q][8] partials
    float*  opart = rsp + (size_t)BB * QS * 8;              // [8][b][Q][Dv] = 32 MB
    // ushort region
    ushort* vhi = (ushort*)(opart + (size_t)8 * BB * QS * DVV);
    ushort* vlo = vhi + (size_t)BB * KSZ * DVV;
    ushort* qh  = vlo + (size_t)BB * KSZ * DVV;
    ushort* ql  = qh  + (size_t)BB * QS * DD;
    ushort* kh  = ql  + (size_t)BB * QS * DD;
    ushort* kl  = kh  + (size_t)BB * KSZ * DD;
    ushort* wqh = kl  + (size_t)BB * KSZ * DD;
    ushort* wql = wqh + (size_t)HH * DD;
    ushort* wkh = wql + (size_t)HH * DD;
    ushort* wkl = wkh + (size_t)HH * DD;

    split_kernel<<<dim3(NSQ + NSK + NWT), 256, 0, stream>>>(
        queries, keys, Wq, Wk, qh, ql, kh, kl, wqh, wql, wkh, wkl);

    projvt_kernel<<<dim3(NPJ + NVT), 256, 0, stream>>>(
        qh, ql, kh, kl, wqh, wql, wkh, wkl, values, eq, ek, vhi, vlo);

    spv_kernel<<<dim3(256), 512, 0, stream>>>(eq, ek, wv, vhi, vlo, opart, rsp);

    norm_kernel<<<dim3(1024), 256, 0, stream>>>(opart, rsp, out);
}